// Round 1
// baseline (3523.265 us; speedup 1.0000x reference)
//
#include <hip/hip_runtime.h>
#include <hip/hip_bf16.h>

#define NN 200000
#define EE 400000
#define HDIM 256
#define LL 4
#define FEAT 10

typedef unsigned short ushort_t;
typedef __attribute__((ext_vector_type(8))) short bf16x8;
typedef __attribute__((ext_vector_type(4))) float f32x4;
typedef __attribute__((ext_vector_type(4))) unsigned int u32x4;

__device__ inline ushort_t f2bf(float f) {
    unsigned int u = __builtin_bit_cast(unsigned int, f);
    unsigned int r = (u + 0x7fffu + ((u >> 16) & 1u)) >> 16;
    return (ushort_t)r;
}

__device__ inline float silu_f(float v) {
    return v / (1.0f + __expf(-v));
}

// 256-thread block reduction of two values (sum a, sum b)
__device__ inline float2 block_sum2(float a, float b) {
    #pragma unroll
    for (int off = 32; off > 0; off >>= 1) {
        a += __shfl_down(a, off, 64);
        b += __shfl_down(b, off, 64);
    }
    __shared__ float red[8];
    int lane = threadIdx.x & 63, w = threadIdx.x >> 6;
    if (lane == 0) { red[2 * w] = a; red[2 * w + 1] = b; }
    __syncthreads();
    float sa = red[0] + red[2] + red[4] + red[6];
    float sb = red[1] + red[3] + red[5] + red[7];
    return make_float2(sa, sb);
}

// x = LayerNorm(silu(emb[z] + feat@Wf + bf), g0, b0); one block per node
__global__ __launch_bounds__(256) void node_init_kernel(
    const int* __restrict__ z, const float* __restrict__ feat,
    const float* __restrict__ emb, const float* __restrict__ Wf,
    const float* __restrict__ bfv, const float* __restrict__ g0,
    const float* __restrict__ b0, float* __restrict__ x)
{
    int n = blockIdx.x, h = threadIdx.x;
    __shared__ float sfeat[FEAT];
    if (h < FEAT) sfeat[h] = feat[n * FEAT + h];
    __syncthreads();
    int zi = z[n];
    float v = emb[zi * HDIM + h] + bfv[h];
    #pragma unroll
    for (int f = 0; f < FEAT; ++f) v += sfeat[f] * Wf[f * HDIM + h];
    float s = silu_f(v);
    float2 ss = block_sum2(s, s * s);
    float mu = ss.x * (1.0f / HDIM);
    float var = ss.y * (1.0f / HDIM) - mu * mu;
    float rs = rsqrtf(var + 1e-5f);
    x[(size_t)n * HDIM + h] = (s - mu) * rs * g0[h] + b0[h];
}

// m = relu(x[src] + silu(edge_attr@We+be)); atomic add into agg[dst]; one block per edge
__global__ __launch_bounds__(256) void message_kernel(
    const int* __restrict__ ei, const float* __restrict__ ea,
    const float* __restrict__ We, const float* __restrict__ be,
    const float* __restrict__ x, float* __restrict__ agg)
{
    int e = blockIdx.x, h = threadIdx.x;
    int src = ei[e];
    int dst = ei[EE + e];
    float4 av = ((const float4*)ea)[e];
    float v = be[h] + av.x * We[h] + av.y * We[HDIM + h]
                    + av.z * We[2 * HDIM + h] + av.w * We[3 * HDIM + h];
    float ev = silu_f(v);
    float m = x[(size_t)src * HDIM + h] + ev;
    m = fmaxf(m, 0.0f);
    unsafeAtomicAdd(&agg[(size_t)dst * HDIM + h], m);
}

// Transpose W1,W2 (L,H,H) f32 -> Wt (L,N=H,K=H) bf16
__global__ __launch_bounds__(256) void prep_w_kernel(
    const float* __restrict__ W1, const float* __restrict__ W2,
    ushort_t* __restrict__ Wt1, ushort_t* __restrict__ Wt2)
{
    int idx = blockIdx.x * 256 + threadIdx.x;   // 0 .. 2*L*65536
    int which = idx >> 18;
    int rem = idx & 262143;                      // l*65536 + n*256 + k
    int l = rem >> 16;
    int n = (rem >> 8) & 255;
    int k = rem & 255;
    const float* W = which ? W2 : W1;
    ushort_t* Wt = which ? Wt2 : Wt1;
    Wt[rem] = f2bf(W[l * 65536 + k * 256 + n]);
}

__global__ __launch_bounds__(256) void batch_out_kernel(
    const int* __restrict__ batch, float* __restrict__ out)
{
    int i = blockIdx.x * 256 + threadIdx.x;
    if (i < NN) out[i] = (float)batch[i];
}

// GEMM: [N,256] x [256,256] via mfma 16x16x32 bf16.
// EPI==0: A = bf16(agg + x), out t = bf16(silu(A@B + bias))
// EPI==1: A = t (bf16),      out h = f32(A@B + bias)
// Block: 256 thr = 4 waves; BM=64, BN=256, BK=64; wave w handles cols w*64..+63.
#define BM 64
#define BK 64
template<int EPI>
__global__ __launch_bounds__(256, 3) void gemm_kernel(
    const float* __restrict__ Aagg, const float* __restrict__ Ax,
    const ushort_t* __restrict__ At, const ushort_t* __restrict__ Bt,
    const float* __restrict__ bias,
    ushort_t* __restrict__ outT, float* __restrict__ outH, int nrows)
{
    __shared__ ushort_t sA[BM][BK];
    __shared__ ushort_t sB[256][BK];
    const int tid = threadIdx.x;
    const int m0 = blockIdx.x * BM;
    const int lane = tid & 63;
    const int w = tid >> 6;
    const int cb = w * 64;

    f32x4 acc[4][4] = {};

    for (int k0 = 0; k0 < HDIM; k0 += BK) {
        // ---- stage A tile [64][64]
        {
            int r = tid >> 2, q = tid & 3;
            int gr = m0 + r; if (gr >= nrows) gr = nrows - 1;
            ushort_t tmp[16];
            if (EPI == 0) {
                const float* pa = Aagg + (size_t)gr * HDIM + k0 + q * 16;
                const float* px = Ax   + (size_t)gr * HDIM + k0 + q * 16;
                #pragma unroll
                for (int i = 0; i < 4; ++i) {
                    f32x4 va = *(const f32x4*)(pa + 4 * i);
                    f32x4 vx = *(const f32x4*)(px + 4 * i);
                    #pragma unroll
                    for (int j = 0; j < 4; ++j)
                        tmp[4 * i + j] = f2bf(va[j] + vx[j]);
                }
            } else {
                const u32x4* p = (const u32x4*)(At + (size_t)gr * HDIM + k0 + q * 16);
                *(u32x4*)&tmp[0] = p[0];
                *(u32x4*)&tmp[8] = p[1];
            }
            int c0 = (2 * q) ^ (r & 7);
            int c1 = (2 * q + 1) ^ (r & 7);
            *(u32x4*)&sA[r][c0 * 8] = *(const u32x4*)&tmp[0];
            *(u32x4*)&sA[r][c1 * 8] = *(const u32x4*)&tmp[8];
        }
        // ---- stage B^T tile [256][64] (Bt is W^T bf16, row-major [n][k])
        {
            int n = tid;
            const ushort_t* p = Bt + n * HDIM + k0;
            #pragma unroll
            for (int c = 0; c < 8; ++c) {
                u32x4 v = *(const u32x4*)(p + c * 8);
                *(u32x4*)&sB[n][(c ^ (n & 7)) * 8] = v;
            }
        }
        __syncthreads();
        // ---- compute
        #pragma unroll
        for (int kk = 0; kk < BK; kk += 32) {
            bf16x8 af[4], bfr[4];
            int cchunk = (kk >> 3) + (lane >> 4);
            #pragma unroll
            for (int m = 0; m < 4; ++m) {
                int r = m * 16 + (lane & 15);
                af[m] = *(const bf16x8*)&sA[r][(cchunk ^ (r & 7)) * 8];
            }
            #pragma unroll
            for (int n = 0; n < 4; ++n) {
                int r = cb + n * 16 + (lane & 15);
                bfr[n] = *(const bf16x8*)&sB[r][(cchunk ^ (r & 7)) * 8];
            }
            #pragma unroll
            for (int m = 0; m < 4; ++m)
                #pragma unroll
                for (int n = 0; n < 4; ++n)
                    acc[m][n] = __builtin_amdgcn_mfma_f32_16x16x32_bf16(
                        af[m], bfr[n], acc[m][n], 0, 0, 0);
        }
        __syncthreads();
    }

    // ---- epilogue
    float bv[4];
    #pragma unroll
    for (int n = 0; n < 4; ++n) bv[n] = bias[cb + n * 16 + (lane & 15)];
    int rbase = (lane >> 4) * 4;
    #pragma unroll
    for (int m = 0; m < 4; ++m) {
        #pragma unroll
        for (int j = 0; j < 4; ++j) {
            int gr = m0 + m * 16 + rbase + j;
            if (gr < nrows) {
                #pragma unroll
                for (int n = 0; n < 4; ++n) {
                    int gc = cb + n * 16 + (lane & 15);
                    float v = acc[m][n][j] + bv[n];
                    if (EPI == 0) {
                        outT[(size_t)gr * HDIM + gc] = f2bf(silu_f(v));
                    } else {
                        outH[(size_t)gr * HDIM + gc] = v;
                    }
                }
            }
        }
    }
}

// x = LayerNorm(x + h, g, b) in place; one block per node
__global__ __launch_bounds__(256) void ln_kernel(
    float* __restrict__ x, const float* __restrict__ hbuf,
    const float* __restrict__ g, const float* __restrict__ b)
{
    int n = blockIdx.x, h = threadIdx.x;
    float v = x[(size_t)n * HDIM + h] + hbuf[(size_t)n * HDIM + h];
    float2 ss = block_sum2(v, v * v);
    float mu = ss.x * (1.0f / HDIM);
    float var = ss.y * (1.0f / HDIM) - mu * mu;
    float rs = rsqrtf(var + 1e-5f);
    x[(size_t)n * HDIM + h] = (v - mu) * rs * g[h] + b[h];
}

extern "C" void kernel_launch(void* const* d_in, const int* in_sizes, int n_in,
                              void* d_out, int out_size, void* d_ws, size_t ws_size,
                              hipStream_t stream)
{
    const int*   z    = (const int*)d_in[0];
    const float* feat = (const float*)d_in[1];
    const int*   ei   = (const int*)d_in[2];
    const float* ea   = (const float*)d_in[3];
    const int*   batch= (const int*)d_in[4];
    const float* emb  = (const float*)d_in[5];
    const float* Wf   = (const float*)d_in[6];
    const float* bfv  = (const float*)d_in[7];
    const float* g0   = (const float*)d_in[8];
    const float* b0   = (const float*)d_in[9];
    const float* We   = (const float*)d_in[10];
    const float* be   = (const float*)d_in[11];
    const float* W1   = (const float*)d_in[12];
    const float* b1   = (const float*)d_in[13];
    const float* W2   = (const float*)d_in[14];
    const float* b2   = (const float*)d_in[15];
    const float* lng  = (const float*)d_in[16];
    const float* lnb  = (const float*)d_in[17];

    float* x    = (float*)d_out;                       // [N,H] fp32
    float* outb = (float*)d_out + (size_t)NN * HDIM;   // [N] batch as float

    char* ws = (char*)d_ws;
    float*    agg = (float*)ws;                                   // N*H f32
    ushort_t* t   = (ushort_t*)(ws + (size_t)NN * HDIM * 4);      // N*H bf16
    ushort_t* Wt1 = (ushort_t*)(ws + (size_t)NN * HDIM * 6);      // L*H*H bf16
    ushort_t* Wt2 = Wt1 + LL * HDIM * HDIM;

    prep_w_kernel<<<2048, 256, 0, stream>>>(W1, W2, Wt1, Wt2);
    node_init_kernel<<<NN, 256, 0, stream>>>(z, feat, emb, Wf, bfv, g0, b0, x);
    batch_out_kernel<<<(NN + 255) / 256, 256, 0, stream>>>(batch, outb);

    for (int l = 0; l < LL; ++l) {
        hipMemsetAsync(agg, 0, (size_t)NN * HDIM * sizeof(float), stream);
        message_kernel<<<EE, 256, 0, stream>>>(ei, ea, We, be, x, agg);
        gemm_kernel<0><<<NN / BM, 256, 0, stream>>>(
            agg, x, nullptr, Wt1 + l * HDIM * HDIM, b1 + l * HDIM, t, nullptr, NN);
        gemm_kernel<1><<<NN / BM, 256, 0, stream>>>(
            nullptr, nullptr, t, Wt2 + l * HDIM * HDIM, b2 + l * HDIM, nullptr, agg, NN);
        ln_kernel<<<NN, 256, 0, stream>>>(x, agg, lng + l * HDIM, lnb + l * HDIM);
    }
}

// Round 2
// 1396.984 us; speedup vs baseline: 2.5221x; 2.5221x over previous
//
#include <hip/hip_runtime.h>
#include <hip/hip_bf16.h>

#define NN 200000
#define EE 400000
#define HDIM 256
#define LL 4
#define FEAT 10

typedef unsigned short ushort_t;
typedef __attribute__((ext_vector_type(8))) short bf16x8;
typedef __attribute__((ext_vector_type(4))) float f32x4;
typedef __attribute__((ext_vector_type(4))) unsigned int u32x4;

__device__ inline ushort_t f2bf(float f) {
    unsigned int u = __builtin_bit_cast(unsigned int, f);
    return (ushort_t)((u + 0x7fffu + ((u >> 16) & 1u)) >> 16);
}
__device__ inline float bf2f(ushort_t s) {
    unsigned int u = ((unsigned int)s) << 16;
    return __builtin_bit_cast(float, u);
}
__device__ inline float silu_f(float v) { return v / (1.0f + __expf(-v)); }

// ---------------- node init: x_bf = LN(silu(emb[z] + feat@Wf + bf)) ; wave per node
__global__ __launch_bounds__(256) void node_init_kernel(
    const int* __restrict__ z, const float* __restrict__ feat,
    const float* __restrict__ emb, const float* __restrict__ Wf,
    const float* __restrict__ bfv, const float* __restrict__ g0,
    const float* __restrict__ b0, ushort_t* __restrict__ xb)
{
    int n = blockIdx.x * 4 + (threadIdx.x >> 6);
    int lane = threadIdx.x & 63, c0 = lane * 4;
    int zi = z[n];
    float4 ev = *(const float4*)&emb[(size_t)zi * HDIM + c0];
    float4 bv = *(const float4*)&bfv[c0];
    float a[4] = {ev.x + bv.x, ev.y + bv.y, ev.z + bv.z, ev.w + bv.w};
    #pragma unroll
    for (int f = 0; f < FEAT; ++f) {
        float sf = feat[n * FEAT + f];
        float4 wv = *(const float4*)&Wf[f * HDIM + c0];
        a[0] += sf * wv.x; a[1] += sf * wv.y; a[2] += sf * wv.z; a[3] += sf * wv.w;
    }
    float s = 0.f, q = 0.f;
    #pragma unroll
    for (int c = 0; c < 4; ++c) { a[c] = silu_f(a[c]); s += a[c]; q += a[c] * a[c]; }
    #pragma unroll
    for (int o = 32; o; o >>= 1) { s += __shfl_xor(s, o, 64); q += __shfl_xor(q, o, 64); }
    float mu = s * (1.0f / HDIM);
    float var = q * (1.0f / HDIM) - mu * mu;
    float rs = rsqrtf(var + 1e-5f);
    float4 gv = *(const float4*)&g0[c0], b2v = *(const float4*)&b0[c0];
    ushort4 o4;
    o4.x = f2bf((a[0] - mu) * rs * gv.x + b2v.x);
    o4.y = f2bf((a[1] - mu) * rs * gv.y + b2v.y);
    o4.z = f2bf((a[2] - mu) * rs * gv.z + b2v.z);
    o4.w = f2bf((a[3] - mu) * rs * gv.w + b2v.w);
    *(ushort4*)&xb[(size_t)n * HDIM + c0] = o4;
}

__global__ __launch_bounds__(256) void batch_out_kernel(
    const int* __restrict__ batch, float* __restrict__ out)
{
    int i = blockIdx.x * 256 + threadIdx.x;
    if (i < NN) out[i] = (float)batch[i];
}

// ---------------- CSR build
__global__ __launch_bounds__(256) void hist_kernel(const int* __restrict__ ei, int* __restrict__ deg)
{
    int i = blockIdx.x * 256 + threadIdx.x;
    if (i < EE) atomicAdd(&deg[ei[EE + i]], 1);
}

__global__ __launch_bounds__(256) void scan_blocks_kernel(
    const int* __restrict__ deg, int* __restrict__ off, int* __restrict__ psum)
{
    int blk = blockIdx.x, t = threadIdx.x;
    int base = blk * 1024 + t * 4;
    int v[4];
    #pragma unroll
    for (int i = 0; i < 4; ++i) v[i] = (base + i < NN) ? deg[base + i] : 0;
    int s = v[0] + v[1] + v[2] + v[3];
    int lane = t & 63, w = t >> 6;
    int ps = s;
    #pragma unroll
    for (int o = 1; o < 64; o <<= 1) { int u = __shfl_up(ps, o, 64); if (lane >= o) ps += u; }
    __shared__ int wt[4];
    if (lane == 63) wt[w] = ps;
    __syncthreads();
    int wbase = 0;
    for (int k = 0; k < w; ++k) wbase += wt[k];
    int run = wbase + ps - s;   // exclusive prefix for this thread
    #pragma unroll
    for (int i = 0; i < 4; ++i) {
        if (base + i < NN) off[base + i] = run;
        run += v[i];
    }
    if (t == 255) psum[blk] = wbase + ps;
}

__global__ __launch_bounds__(256) void scan_top_kernel(int* __restrict__ psum, int nb)
{
    int t = threadIdx.x;
    int v = (t < nb) ? psum[t] : 0;
    int lane = t & 63, w = t >> 6;
    int ps = v;
    #pragma unroll
    for (int o = 1; o < 64; o <<= 1) { int u = __shfl_up(ps, o, 64); if (lane >= o) ps += u; }
    __shared__ int wt[4];
    if (lane == 63) wt[w] = ps;
    __syncthreads();
    int wbase = 0;
    for (int k = 0; k < w; ++k) wbase += wt[k];
    if (t < nb) psum[t] = wbase + ps - v;   // exclusive
}

__global__ __launch_bounds__(256) void scan_add_kernel(
    int* __restrict__ off, const int* __restrict__ psum, int* __restrict__ cursor)
{
    int i = blockIdx.x * 256 + threadIdx.x;
    if (i < NN) {
        int o = off[i] + psum[i >> 10];
        off[i] = o;
        cursor[i] = o;
        if (i == NN - 1) off[NN] = EE;
    }
}

__global__ __launch_bounds__(256) void scatter_kernel(
    const int* __restrict__ ei, const float* __restrict__ ea,
    int* __restrict__ cursor, int* __restrict__ srcs, float4* __restrict__ eaf)
{
    int i = blockIdx.x * 256 + threadIdx.x;
    if (i < EE) {
        int dst = ei[EE + i];
        int pos = atomicAdd(&cursor[dst], 1);
        srcs[pos] = ei[i];
        eaf[pos] = ((const float4*)ea)[i];
    }
}

// ---------------- aggregation (CSR gather) + residual + cast: U = bf16(sum relu(x[src]+e) + x)
__global__ __launch_bounds__(256) void agg_kernel(
    const int* __restrict__ off, const int* __restrict__ srcs,
    const float4* __restrict__ eaf, const float* __restrict__ We,
    const float* __restrict__ be, const ushort_t* __restrict__ xb,
    ushort_t* __restrict__ U)
{
    int n = blockIdx.x * 4 + (threadIdx.x >> 6);
    int lane = threadIdx.x & 63, c0 = lane * 4;
    float4 w0 = *(const float4*)&We[c0];
    float4 w1 = *(const float4*)&We[HDIM + c0];
    float4 w2 = *(const float4*)&We[2 * HDIM + c0];
    float4 w3 = *(const float4*)&We[3 * HDIM + c0];
    float4 bev = *(const float4*)&be[c0];
    float acc[4] = {0.f, 0.f, 0.f, 0.f};
    int beg = off[n], end = off[n + 1];
    for (int p = beg; p < end; ++p) {
        int src = srcs[p];
        float4 av = eaf[p];
        ushort4 xs = *(const ushort4*)&xb[(size_t)src * HDIM + c0];
        float e0 = silu_f(bev.x + av.x * w0.x + av.y * w1.x + av.z * w2.x + av.w * w3.x);
        float e1 = silu_f(bev.y + av.x * w0.y + av.y * w1.y + av.z * w2.y + av.w * w3.y);
        float e2 = silu_f(bev.z + av.x * w0.z + av.y * w1.z + av.z * w2.z + av.w * w3.z);
        float e3 = silu_f(bev.w + av.x * w0.w + av.y * w1.w + av.z * w2.w + av.w * w3.w);
        acc[0] += fmaxf(bf2f(xs.x) + e0, 0.f);
        acc[1] += fmaxf(bf2f(xs.y) + e1, 0.f);
        acc[2] += fmaxf(bf2f(xs.z) + e2, 0.f);
        acc[3] += fmaxf(bf2f(xs.w) + e3, 0.f);
    }
    ushort4 xo = *(const ushort4*)&xb[(size_t)n * HDIM + c0];
    ushort4 o;
    o.x = f2bf(acc[0] + bf2f(xo.x));
    o.y = f2bf(acc[1] + bf2f(xo.y));
    o.z = f2bf(acc[2] + bf2f(xo.z));
    o.w = f2bf(acc[3] + bf2f(xo.w));
    *(ushort4*)&U[(size_t)n * HDIM + c0] = o;
}

// ---------------- W transpose to bf16
__global__ __launch_bounds__(256) void prep_w_kernel(
    const float* __restrict__ W1, const float* __restrict__ W2,
    ushort_t* __restrict__ Wt1, ushort_t* __restrict__ Wt2)
{
    int idx = blockIdx.x * 256 + threadIdx.x;
    int which = idx >> 18;
    int rem = idx & 262143;
    int l = rem >> 16;
    int n = (rem >> 8) & 255;
    int k = rem & 255;
    const float* W = which ? W2 : W1;
    ushort_t* Wt = which ? Wt2 : Wt1;
    Wt[rem] = f2bf(W[l * 65536 + k * 256 + n]);
}

// ---------------- GEMM: O = epi(A @ Bt^T + bias), A,O bf16 [N,256], may alias (same rows only)
#define BM 64
#define BK 64
template<int EPI>  // 0: silu, 1: identity
__global__ __launch_bounds__(256, 3) void gemm_kernel(
    const ushort_t* A, const ushort_t* __restrict__ Bt,
    const float* __restrict__ bias, ushort_t* O)
{
    __shared__ ushort_t sA[BM][BK];
    __shared__ ushort_t sB[256][BK];
    const int tid = threadIdx.x;
    const int m0 = blockIdx.x * BM;
    const int lane = tid & 63;
    const int w = tid >> 6;
    const int cb = w * 64;

    f32x4 acc[4][4] = {};

    for (int k0 = 0; k0 < HDIM; k0 += BK) {
        {   // stage A tile [64][64] bf16, XOR-swizzled
            int r = tid >> 2, q = tid & 3;
            int gr = m0 + r;
            const u32x4* p = (const u32x4*)(A + (size_t)gr * HDIM + k0 + q * 16);
            u32x4 t0 = p[0], t1 = p[1];
            int ch0 = (2 * q) ^ (r & 7);
            int ch1 = (2 * q + 1) ^ (r & 7);
            *(u32x4*)&sA[r][ch0 * 8] = t0;
            *(u32x4*)&sA[r][ch1 * 8] = t1;
        }
        {   // stage B^T tile [256][64]
            int nn = tid;
            const ushort_t* p = Bt + nn * HDIM + k0;
            #pragma unroll
            for (int c = 0; c < 8; ++c) {
                u32x4 v = *(const u32x4*)(p + c * 8);
                *(u32x4*)&sB[nn][(c ^ (nn & 7)) * 8] = v;
            }
        }
        __syncthreads();
        #pragma unroll
        for (int kk = 0; kk < BK; kk += 32) {
            bf16x8 af[4], bfr[4];
            int cchunk = (kk >> 3) + (lane >> 4);
            #pragma unroll
            for (int m = 0; m < 4; ++m) {
                int r = m * 16 + (lane & 15);
                af[m] = *(const bf16x8*)&sA[r][(cchunk ^ (r & 7)) * 8];
            }
            #pragma unroll
            for (int nf = 0; nf < 4; ++nf) {
                int r = cb + nf * 16 + (lane & 15);
                bfr[nf] = *(const bf16x8*)&sB[r][(cchunk ^ (r & 7)) * 8];
            }
            #pragma unroll
            for (int m = 0; m < 4; ++m)
                #pragma unroll
                for (int nf = 0; nf < 4; ++nf)
                    acc[m][nf] = __builtin_amdgcn_mfma_f32_16x16x32_bf16(
                        af[m], bfr[nf], acc[m][nf], 0, 0, 0);
        }
        __syncthreads();
    }

    float bv[4];
    #pragma unroll
    for (int nf = 0; nf < 4; ++nf) bv[nf] = bias[cb + nf * 16 + (lane & 15)];
    int rbase = (lane >> 4) * 4;
    #pragma unroll
    for (int m = 0; m < 4; ++m) {
        #pragma unroll
        for (int j = 0; j < 4; ++j) {
            int gr = m0 + m * 16 + rbase + j;
            #pragma unroll
            for (int nf = 0; nf < 4; ++nf) {
                int gc = cb + nf * 16 + (lane & 15);
                float v = acc[m][nf][j] + bv[nf];
                if (EPI == 0) v = silu_f(v);
                O[(size_t)gr * HDIM + gc] = f2bf(v);
            }
        }
    }
}

// ---------------- LayerNorm: x_bf = LN(x_bf + U) ; optional f32 out on last layer
__global__ __launch_bounds__(256) void ln_kernel(
    const ushort_t* __restrict__ U, ushort_t* __restrict__ xb,
    const float* __restrict__ g, const float* __restrict__ b,
    float* __restrict__ xout)
{
    int n = blockIdx.x * 4 + (threadIdx.x >> 6);
    int lane = threadIdx.x & 63, c0 = lane * 4;
    ushort4 hu = *(const ushort4*)&U[(size_t)n * HDIM + c0];
    ushort4 xu = *(const ushort4*)&xb[(size_t)n * HDIM + c0];
    float v[4] = {bf2f(hu.x) + bf2f(xu.x), bf2f(hu.y) + bf2f(xu.y),
                  bf2f(hu.z) + bf2f(xu.z), bf2f(hu.w) + bf2f(xu.w)};
    float s = 0.f, q = 0.f;
    #pragma unroll
    for (int c = 0; c < 4; ++c) { s += v[c]; q += v[c] * v[c]; }
    #pragma unroll
    for (int o = 32; o; o >>= 1) { s += __shfl_xor(s, o, 64); q += __shfl_xor(q, o, 64); }
    float mu = s * (1.0f / HDIM);
    float var = q * (1.0f / HDIM) - mu * mu;
    float rs = rsqrtf(var + 1e-5f);
    float4 gv = *(const float4*)&g[c0], bv = *(const float4*)&b[c0];
    float o0 = (v[0] - mu) * rs * gv.x + bv.x;
    float o1 = (v[1] - mu) * rs * gv.y + bv.y;
    float o2 = (v[2] - mu) * rs * gv.z + bv.z;
    float o3 = (v[3] - mu) * rs * gv.w + bv.w;
    ushort4 o4;
    o4.x = f2bf(o0); o4.y = f2bf(o1); o4.z = f2bf(o2); o4.w = f2bf(o3);
    *(ushort4*)&xb[(size_t)n * HDIM + c0] = o4;
    if (xout) {
        float4 fo; fo.x = o0; fo.y = o1; fo.z = o2; fo.w = o3;
        *(float4*)&xout[(size_t)n * HDIM + c0] = fo;
    }
}

extern "C" void kernel_launch(void* const* d_in, const int* in_sizes, int n_in,
                              void* d_out, int out_size, void* d_ws, size_t ws_size,
                              hipStream_t stream)
{
    const int*   z    = (const int*)d_in[0];
    const float* feat = (const float*)d_in[1];
    const int*   ei   = (const int*)d_in[2];
    const float* ea   = (const float*)d_in[3];
    const int*   batch= (const int*)d_in[4];
    const float* emb  = (const float*)d_in[5];
    const float* Wf   = (const float*)d_in[6];
    const float* bfv  = (const float*)d_in[7];
    const float* g0   = (const float*)d_in[8];
    const float* b0   = (const float*)d_in[9];
    const float* We   = (const float*)d_in[10];
    const float* be   = (const float*)d_in[11];
    const float* W1   = (const float*)d_in[12];
    const float* b1   = (const float*)d_in[13];
    const float* W2   = (const float*)d_in[14];
    const float* b2   = (const float*)d_in[15];
    const float* lng  = (const float*)d_in[16];
    const float* lnb  = (const float*)d_in[17];

    float* x    = (float*)d_out;
    float* outb = (float*)d_out + (size_t)NN * HDIM;

    char* ws = (char*)d_ws;
    ushort_t* xb   = (ushort_t*)ws;                         // 102,400,000 B
    ushort_t* U    = (ushort_t*)(ws + 102400000);           // 102,400,000 B
    float4*   eaf  = (float4*)(ws + 204800000);             // 6,400,000 B
    int*      srcs = (int*)(ws + 211200000);                // 1,600,000 B
    int*      off  = (int*)(ws + 212800000);                // 800,016 B
    int*      cursor = (int*)(ws + 213600016);              // 800,000 B
    int*      deg  = (int*)(ws + 214400016);                // 800,000 B
    int*      psum = (int*)(ws + 215200016);                // 1,008 B
    ushort_t* Wt1  = (ushort_t*)(ws + 215201024);           // 524,288 B
    ushort_t* Wt2  = Wt1 + LL * HDIM * HDIM;                // 524,288 B

    prep_w_kernel<<<2048, 256, 0, stream>>>(W1, W2, Wt1, Wt2);
    batch_out_kernel<<<782, 256, 0, stream>>>(batch, outb);
    node_init_kernel<<<NN / 4, 256, 0, stream>>>(z, feat, emb, Wf, bfv, g0, b0, xb);

    hipMemsetAsync(deg, 0, NN * sizeof(int), stream);
    hist_kernel<<<1563, 256, 0, stream>>>(ei, deg);
    scan_blocks_kernel<<<196, 256, 0, stream>>>(deg, off, psum);
    scan_top_kernel<<<1, 256, 0, stream>>>(psum, 196);
    scan_add_kernel<<<782, 256, 0, stream>>>(off, psum, cursor);
    scatter_kernel<<<1563, 256, 0, stream>>>(ei, ea, cursor, srcs, eaf);

    for (int l = 0; l < LL; ++l) {
        agg_kernel<<<NN / 4, 256, 0, stream>>>(off, srcs, eaf, We, be, xb, U);
        gemm_kernel<0><<<NN / BM, 256, 0, stream>>>(U, Wt1 + l * HDIM * HDIM, b1 + l * HDIM, U);
        gemm_kernel<1><<<NN / BM, 256, 0, stream>>>(U, Wt2 + l * HDIM * HDIM, b2 + l * HDIM, U);
        ln_kernel<<<NN / 4, 256, 0, stream>>>(U, xb, lng + l * HDIM, lnb + l * HDIM,
                                              (l == LL - 1) ? x : nullptr);
    }
}

// Round 3
// 1384.152 us; speedup vs baseline: 2.5454x; 1.0093x over previous
//
#include <hip/hip_runtime.h>
#include <hip/hip_bf16.h>

#define NN 200000
#define EE 400000
#define HDIM 256
#define LL 4
#define FEAT 10

typedef unsigned short ushort_t;
typedef __attribute__((ext_vector_type(8))) short bf16x8;
typedef __attribute__((ext_vector_type(8))) unsigned short u16x8;
typedef __attribute__((ext_vector_type(4))) float f32x4;
typedef __attribute__((ext_vector_type(4))) unsigned int u32x4;

__device__ inline ushort_t f2bf(float f) {
    unsigned int u = __builtin_bit_cast(unsigned int, f);
    return (ushort_t)((u + 0x7fffu + ((u >> 16) & 1u)) >> 16);
}
__device__ inline float bf2f(ushort_t s) {
    unsigned int u = ((unsigned int)s) << 16;
    return __builtin_bit_cast(float, u);
}
__device__ inline float silu_f(float v) { return v / (1.0f + __expf(-v)); }

// ---------------- node init: xb = LN(silu(emb[z] + feat@Wf + bf)); 32 lanes/node, 8 elems/lane
__global__ __launch_bounds__(256) void node_init_kernel(
    const int* __restrict__ z, const float* __restrict__ feat,
    const float* __restrict__ emb, const float* __restrict__ Wf,
    const float* __restrict__ bfv, const float* __restrict__ g0,
    const float* __restrict__ b0, ushort_t* __restrict__ xb)
{
    int n = blockIdx.x * 8 + (threadIdx.x >> 5);
    int nl = threadIdx.x & 31, c0 = nl * 8;
    int zi = z[n];
    float a[8];
    {
        f32x4 e0 = *(const f32x4*)&emb[(size_t)zi * HDIM + c0];
        f32x4 e1 = *(const f32x4*)&emb[(size_t)zi * HDIM + c0 + 4];
        f32x4 v0 = *(const f32x4*)&bfv[c0];
        f32x4 v1 = *(const f32x4*)&bfv[c0 + 4];
        #pragma unroll
        for (int j = 0; j < 4; ++j) { a[j] = e0[j] + v0[j]; a[4 + j] = e1[j] + v1[j]; }
    }
    #pragma unroll
    for (int f = 0; f < FEAT; ++f) {
        float sf = feat[n * FEAT + f];
        f32x4 w0 = *(const f32x4*)&Wf[f * HDIM + c0];
        f32x4 w1 = *(const f32x4*)&Wf[f * HDIM + c0 + 4];
        #pragma unroll
        for (int j = 0; j < 4; ++j) { a[j] += sf * w0[j]; a[4 + j] += sf * w1[j]; }
    }
    float s = 0.f, q = 0.f;
    #pragma unroll
    for (int c = 0; c < 8; ++c) { a[c] = silu_f(a[c]); s += a[c]; q += a[c] * a[c]; }
    #pragma unroll
    for (int o = 16; o; o >>= 1) { s += __shfl_xor(s, o, 64); q += __shfl_xor(q, o, 64); }
    float mu = s * (1.0f / HDIM);
    float var = q * (1.0f / HDIM) - mu * mu;
    float rs = rsqrtf(var + 1e-5f);
    u16x8 o8;
    #pragma unroll
    for (int c = 0; c < 8; ++c) {
        float g = g0[c0 + c], b = b0[c0 + c];
        o8[c] = f2bf((a[c] - mu) * rs * g + b);
    }
    *(u16x8*)&xb[(size_t)n * HDIM + c0] = o8;
}

__global__ __launch_bounds__(256) void batch_out_kernel(
    const int* __restrict__ batch, float* __restrict__ out)
{
    int i = blockIdx.x * 256 + threadIdx.x;
    if (i < NN) out[i] = (float)batch[i];
}

// ---------------- CSR build
__global__ __launch_bounds__(256) void hist_kernel(const int* __restrict__ ei, int* __restrict__ deg)
{
    int i = blockIdx.x * 256 + threadIdx.x;
    if (i < EE) atomicAdd(&deg[ei[EE + i]], 1);
}

__global__ __launch_bounds__(256) void scan_blocks_kernel(
    const int* __restrict__ deg, int* __restrict__ off, int* __restrict__ psum)
{
    int blk = blockIdx.x, t = threadIdx.x;
    int base = blk * 1024 + t * 4;
    int v[4];
    #pragma unroll
    for (int i = 0; i < 4; ++i) v[i] = (base + i < NN) ? deg[base + i] : 0;
    int s = v[0] + v[1] + v[2] + v[3];
    int lane = t & 63, w = t >> 6;
    int ps = s;
    #pragma unroll
    for (int o = 1; o < 64; o <<= 1) { int u = __shfl_up(ps, o, 64); if (lane >= o) ps += u; }
    __shared__ int wt[4];
    if (lane == 63) wt[w] = ps;
    __syncthreads();
    int wbase = 0;
    for (int k = 0; k < w; ++k) wbase += wt[k];
    int run = wbase + ps - s;
    #pragma unroll
    for (int i = 0; i < 4; ++i) {
        if (base + i < NN) off[base + i] = run;
        run += v[i];
    }
    if (t == 255) psum[blk] = wbase + ps;
}

__global__ __launch_bounds__(256) void scan_top_kernel(int* __restrict__ psum, int nb)
{
    int t = threadIdx.x;
    int v = (t < nb) ? psum[t] : 0;
    int lane = t & 63, w = t >> 6;
    int ps = v;
    #pragma unroll
    for (int o = 1; o < 64; o <<= 1) { int u = __shfl_up(ps, o, 64); if (lane >= o) ps += u; }
    __shared__ int wt[4];
    if (lane == 63) wt[w] = ps;
    __syncthreads();
    int wbase = 0;
    for (int k = 0; k < w; ++k) wbase += wt[k];
    if (t < nb) psum[t] = wbase + ps - v;
}

__global__ __launch_bounds__(256) void scan_add_kernel(
    int* __restrict__ off, const int* __restrict__ psum, int* __restrict__ cursor)
{
    int i = blockIdx.x * 256 + threadIdx.x;
    if (i < NN) {
        int o = off[i] + psum[i >> 10];
        off[i] = o;
        cursor[i] = o;
        if (i == NN - 1) off[NN] = EE;
    }
}

__global__ __launch_bounds__(256) void scatter_kernel(
    const int* __restrict__ ei, const float* __restrict__ ea,
    int* __restrict__ cursor, int* __restrict__ srcs, float4* __restrict__ eaf)
{
    int i = blockIdx.x * 256 + threadIdx.x;
    if (i < EE) {
        int dst = ei[EE + i];
        int pos = atomicAdd(&cursor[dst], 1);
        srcs[pos] = ei[i];
        eaf[pos] = ((const float4*)ea)[i];
    }
}

// ---------------- aggregation: U = bf16(sum relu(x[src]+e) + x); 32 lanes/node
__global__ __launch_bounds__(256) void agg_kernel(
    const int* __restrict__ off, const int* __restrict__ srcs,
    const float4* __restrict__ eaf, const float* __restrict__ We,
    const float* __restrict__ be, const ushort_t* __restrict__ xb,
    ushort_t* __restrict__ U)
{
    int n = blockIdx.x * 8 + (threadIdx.x >> 5);
    int nl = threadIdx.x & 31, c0 = nl * 8;
    float w[4][8], bev[8];
    #pragma unroll
    for (int r = 0; r < 4; ++r) {
        f32x4 wa = *(const f32x4*)&We[r * HDIM + c0];
        f32x4 wb = *(const f32x4*)&We[r * HDIM + c0 + 4];
        #pragma unroll
        for (int j = 0; j < 4; ++j) { w[r][j] = wa[j]; w[r][4 + j] = wb[j]; }
    }
    {
        f32x4 ba = *(const f32x4*)&be[c0];
        f32x4 bb = *(const f32x4*)&be[c0 + 4];
        #pragma unroll
        for (int j = 0; j < 4; ++j) { bev[j] = ba[j]; bev[4 + j] = bb[j]; }
    }
    float acc[8] = {};
    int beg = off[n], end = off[n + 1];
    for (int p = beg; p < end; ++p) {
        int src = srcs[p];
        float4 av = eaf[p];
        u16x8 xs = *(const u16x8*)&xb[(size_t)src * HDIM + c0];
        #pragma unroll
        for (int j = 0; j < 8; ++j) {
            float e = silu_f(bev[j] + av.x * w[0][j] + av.y * w[1][j]
                                    + av.z * w[2][j] + av.w * w[3][j]);
            acc[j] += fmaxf(bf2f(xs[j]) + e, 0.f);
        }
    }
    u16x8 xo = *(const u16x8*)&xb[(size_t)n * HDIM + c0];
    u16x8 o8;
    #pragma unroll
    for (int j = 0; j < 8; ++j) o8[j] = f2bf(acc[j] + bf2f(xo[j]));
    *(u16x8*)&U[(size_t)n * HDIM + c0] = o8;
}

// ---------------- weights: W[l][k][n] f32 -> chunked pre-swizzled bf16
// Wc[l][kc][n][cp][e] = bf16(W[l][kc*64 + (cp ^ (n&7))*8 + e][n])
__global__ __launch_bounds__(256) void prep_w_kernel(
    const float* __restrict__ W1, const float* __restrict__ W2,
    ushort_t* __restrict__ Wc1, ushort_t* __restrict__ Wc2)
{
    int idx = blockIdx.x * 256 + threadIdx.x;   // 2 * 4 * 65536
    int which = idx >> 18;
    int rem = idx & 0x3FFFF;
    int l = rem >> 16;
    int t = rem & 0xFFFF;
    int kc = t >> 14;
    int n = (t >> 6) & 255;
    int cpe = t & 63;
    int cp = cpe >> 3, e = cpe & 7;
    int ktrue = kc * 64 + ((cp ^ (n & 7)) << 3) + e;
    const float* W = which ? W2 : W1;
    ushort_t* Wc = which ? Wc2 : Wc1;
    Wc[rem] = f2bf(W[l * 65536 + ktrue * 256 + n]);
}

// ---------------- fused MLP + LayerNorm
// block: 64 rows, 256 thr (4 waves), wave w owns cols w*64..+63
// t = silu(U@W1+b1) (LDS); h = t@W2+b2; xout = LN(xin + h); LAST: also f32 out
template<int LAST>
__global__ __launch_bounds__(256, 2) void mlp_kernel(
    const ushort_t* __restrict__ U, const ushort_t* __restrict__ Wc1,
    const ushort_t* __restrict__ Wc2, const float* __restrict__ b1,
    const float* __restrict__ b2, const float* __restrict__ lng,
    const float* __restrict__ lnb, const ushort_t* __restrict__ xin,
    ushort_t* __restrict__ xout, float* __restrict__ xf32)
{
    __shared__ ushort_t sA[64][256];   // U tile -> t tile -> out tile
    __shared__ ushort_t sB[256][64];   // weight chunk -> x-residual tile
    __shared__ float sRed[4][64][2];
    const int tid = threadIdx.x;
    const int m0 = blockIdx.x * 64;
    const int lane = tid & 63;
    const int w = tid >> 6;
    const int cb = w * 64;
    const int lg = lane >> 4;
    const int ll = lane & 15;

    // stage A = U rows (swizzled 16B chunks)
    #pragma unroll
    for (int it = 0; it < 8; ++it) {
        int idx = tid + it * 256;
        int r = idx >> 5, ch = idx & 31;
        u32x4 v = *(const u32x4*)(U + (((size_t)(m0 + r)) << 8) + ch * 8);
        *(u32x4*)&sA[r][((ch ^ (r & 7)) << 3)] = v;
    }

    f32x4 acc[4][4] = {};

    // ---- GEMM1: acc = U @ W1^T-chunks
    for (int kc = 0; kc < 4; ++kc) {
        #pragma unroll
        for (int it = 0; it < 16; ++it) {
            int idx = tid + it * 256;
            u32x4 v = *(const u32x4*)(Wc1 + kc * 16384 + idx * 8);
            *(u32x4*)(&sB[0][0] + idx * 8) = v;
        }
        __syncthreads();
        #pragma unroll
        for (int kk = 0; kk < 64; kk += 32) {
            bf16x8 af[4], bfr[4];
            int chA = kc * 8 + (kk >> 3) + lg;
            int chB = (kk >> 3) + lg;
            #pragma unroll
            for (int m = 0; m < 4; ++m) {
                int r = m * 16 + ll;
                af[m] = *(const bf16x8*)&sA[r][((chA ^ (r & 7)) << 3)];
            }
            #pragma unroll
            for (int nf = 0; nf < 4; ++nf) {
                int rn = cb + nf * 16 + ll;
                bfr[nf] = *(const bf16x8*)&sB[rn][((chB ^ (rn & 7)) << 3)];
            }
            #pragma unroll
            for (int m = 0; m < 4; ++m)
                #pragma unroll
                for (int nf = 0; nf < 4; ++nf)
                    acc[m][nf] = __builtin_amdgcn_mfma_f32_16x16x32_bf16(
                        af[m], bfr[nf], acc[m][nf], 0, 0, 0);
        }
        __syncthreads();
    }

    // ---- t = silu(acc + b1) -> sA (overwrite, swizzled)
    {
        float bv1[4];
        #pragma unroll
        for (int nf = 0; nf < 4; ++nf) bv1[nf] = b1[cb + nf * 16 + ll];
        #pragma unroll
        for (int m = 0; m < 4; ++m)
            #pragma unroll
            for (int nf = 0; nf < 4; ++nf)
                #pragma unroll
                for (int j = 0; j < 4; ++j) {
                    int r = m * 16 + lg * 4 + j;
                    int c = cb + nf * 16 + ll;
                    float v = silu_f(acc[m][nf][j] + bv1[nf]);
                    sA[r][(((c >> 3) ^ (r & 7)) << 3) + (c & 7)] = f2bf(v);
                    acc[m][nf][j] = 0.f;
                }
    }

    // ---- GEMM2: acc = t @ W2^T-chunks  (first sync covers t-writes)
    for (int kc = 0; kc < 4; ++kc) {
        #pragma unroll
        for (int it = 0; it < 16; ++it) {
            int idx = tid + it * 256;
            u32x4 v = *(const u32x4*)(Wc2 + kc * 16384 + idx * 8);
            *(u32x4*)(&sB[0][0] + idx * 8) = v;
        }
        __syncthreads();
        #pragma unroll
        for (int kk = 0; kk < 64; kk += 32) {
            bf16x8 af[4], bfr[4];
            int chA = kc * 8 + (kk >> 3) + lg;
            int chB = (kk >> 3) + lg;
            #pragma unroll
            for (int m = 0; m < 4; ++m) {
                int r = m * 16 + ll;
                af[m] = *(const bf16x8*)&sA[r][((chA ^ (r & 7)) << 3)];
            }
            #pragma unroll
            for (int nf = 0; nf < 4; ++nf) {
                int rn = cb + nf * 16 + ll;
                bfr[nf] = *(const bf16x8*)&sB[rn][((chB ^ (rn & 7)) << 3)];
            }
            #pragma unroll
            for (int m = 0; m < 4; ++m)
                #pragma unroll
                for (int nf = 0; nf < 4; ++nf)
                    acc[m][nf] = __builtin_amdgcn_mfma_f32_16x16x32_bf16(
                        af[m], bfr[nf], acc[m][nf], 0, 0, 0);
        }
        __syncthreads();
    }

    // ---- stage x-residual tile into sB region (swizzled)
    ushort_t (*sX)[256] = reinterpret_cast<ushort_t (*)[256]>(&sB[0][0]);
    #pragma unroll
    for (int it = 0; it < 8; ++it) {
        int idx = tid + it * 256;
        int r = idx >> 5, ch = idx & 31;
        u32x4 v = *(const u32x4*)(xin + (((size_t)(m0 + r)) << 8) + ch * 8);
        *(u32x4*)&sX[r][((ch ^ (r & 7)) << 3)] = v;
    }
    __syncthreads();

    // ---- v = x + h (+b2); row partial sums
    float bv2[4], gv[4], bbv[4];
    #pragma unroll
    for (int nf = 0; nf < 4; ++nf) {
        int c = cb + nf * 16 + ll;
        bv2[nf] = b2[c]; gv[nf] = lng[c]; bbv[nf] = lnb[c];
    }
    float psum[4][4], psq[4][4];
    #pragma unroll
    for (int m = 0; m < 4; ++m)
        #pragma unroll
        for (int j = 0; j < 4; ++j) {
            int r = m * 16 + lg * 4 + j;
            float s = 0.f, q = 0.f;
            #pragma unroll
            for (int nf = 0; nf < 4; ++nf) {
                int c = cb + nf * 16 + ll;
                float xres = bf2f(sX[r][(((c >> 3) ^ (r & 7)) << 3) + (c & 7)]);
                float val = acc[m][nf][j] + bv2[nf] + xres;
                acc[m][nf][j] = val;
                s += val; q += val * val;
            }
            psum[m][j] = s; psq[m][j] = q;
        }
    #pragma unroll
    for (int o = 8; o; o >>= 1) {
        #pragma unroll
        for (int m = 0; m < 4; ++m)
            #pragma unroll
            for (int j = 0; j < 4; ++j) {
                psum[m][j] += __shfl_xor(psum[m][j], o, 64);
                psq[m][j]  += __shfl_xor(psq[m][j], o, 64);
            }
    }
    if (ll == 0) {
        #pragma unroll
        for (int m = 0; m < 4; ++m)
            #pragma unroll
            for (int j = 0; j < 4; ++j) {
                int r = m * 16 + lg * 4 + j;
                sRed[w][r][0] = psum[m][j];
                sRed[w][r][1] = psq[m][j];
            }
    }
    __syncthreads();

    // ---- normalize, write out tile (sA reuse, swizzled)
    ushort_t (*sOut)[256] = reinterpret_cast<ushort_t (*)[256]>(&sA[0][0]);
    #pragma unroll
    for (int m = 0; m < 4; ++m)
        #pragma unroll
        for (int j = 0; j < 4; ++j) {
            int r = m * 16 + lg * 4 + j;
            float s = sRed[0][r][0] + sRed[1][r][0] + sRed[2][r][0] + sRed[3][r][0];
            float q = sRed[0][r][1] + sRed[1][r][1] + sRed[2][r][1] + sRed[3][r][1];
            float mu = s * (1.0f / HDIM);
            float var = q * (1.0f / HDIM) - mu * mu;
            float rs = rsqrtf(var + 1e-5f);
            #pragma unroll
            for (int nf = 0; nf < 4; ++nf) {
                int c = cb + nf * 16 + ll;
                float val = (acc[m][nf][j] - mu) * rs * gv[nf] + bbv[nf];
                sOut[r][(((c >> 3) ^ (r & 7)) << 3) + (c & 7)] = f2bf(val);
            }
        }
    __syncthreads();

    // ---- coalesced copy-out
    #pragma unroll
    for (int it = 0; it < 8; ++it) {
        int idx = tid + it * 256;
        int r = idx >> 5, ch = idx & 31;
        u32x4 v = *(const u32x4*)&sOut[r][((ch ^ (r & 7)) << 3)];
        *(u32x4*)(xout + (((size_t)(m0 + r)) << 8) + ch * 8) = v;
        if (LAST) {
            float* dst = xf32 + (((size_t)(m0 + r)) << 8) + ch * 8;
            f32x4 f0, f1;
            #pragma unroll
            for (int k = 0; k < 4; ++k) {
                unsigned int u = v[k];
                float lo = __builtin_bit_cast(float, u << 16);
                float hi = __builtin_bit_cast(float, u & 0xFFFF0000u);
                if (k < 2) { f0[2 * k] = lo; f0[2 * k + 1] = hi; }
                else { f1[2 * (k - 2)] = lo; f1[2 * (k - 2) + 1] = hi; }
            }
            *(f32x4*)dst = f0;
            *(f32x4*)(dst + 4) = f1;
        }
    }
}

extern "C" void kernel_launch(void* const* d_in, const int* in_sizes, int n_in,
                              void* d_out, int out_size, void* d_ws, size_t ws_size,
                              hipStream_t stream)
{
    const int*   z    = (const int*)d_in[0];
    const float* feat = (const float*)d_in[1];
    const int*   ei   = (const int*)d_in[2];
    const float* ea   = (const float*)d_in[3];
    const int*   batch= (const int*)d_in[4];
    const float* emb  = (const float*)d_in[5];
    const float* Wf   = (const float*)d_in[6];
    const float* bfv  = (const float*)d_in[7];
    const float* g0   = (const float*)d_in[8];
    const float* b0   = (const float*)d_in[9];
    const float* We   = (const float*)d_in[10];
    const float* be   = (const float*)d_in[11];
    const float* W1   = (const float*)d_in[12];
    const float* b1   = (const float*)d_in[13];
    const float* W2   = (const float*)d_in[14];
    const float* b2   = (const float*)d_in[15];
    const float* lng  = (const float*)d_in[16];
    const float* lnb  = (const float*)d_in[17];

    float* x    = (float*)d_out;
    float* outb = (float*)d_out + (size_t)NN * HDIM;

    char* ws = (char*)d_ws;
    ushort_t* xb0  = (ushort_t*)ws;                         // 102,400,000 B
    ushort_t* xb1  = (ushort_t*)(ws + 102400000);           // 102,400,000 B
    ushort_t* U    = (ushort_t*)(ws + 204800000);           // 102,400,000 B
    float4*   eaf  = (float4*)(ws + 307200000);             // 6,400,000 B
    int*      srcs = (int*)(ws + 313600000);                // 1,600,000 B
    int*      off  = (int*)(ws + 315200000);                // 800,016 B
    int*      cursor = (int*)(ws + 316000016);              // 800,000 B
    int*      deg  = (int*)(ws + 316800016);                // 800,000 B
    int*      psum = (int*)(ws + 317600016);                // 1,008 B
    ushort_t* Wc1  = (ushort_t*)(ws + 317601024);           // 524,288 B
    ushort_t* Wc2  = Wc1 + LL * HDIM * HDIM;                // 524,288 B

    prep_w_kernel<<<2048, 256, 0, stream>>>(W1, W2, Wc1, Wc2);
    batch_out_kernel<<<782, 256, 0, stream>>>(batch, outb);
    node_init_kernel<<<NN / 8, 256, 0, stream>>>(z, feat, emb, Wf, bfv, g0, b0, xb0);

    hipMemsetAsync(deg, 0, NN * sizeof(int), stream);
    hist_kernel<<<1563, 256, 0, stream>>>(ei, deg);
    scan_blocks_kernel<<<196, 256, 0, stream>>>(deg, off, psum);
    scan_top_kernel<<<1, 256, 0, stream>>>(psum, 196);
    scan_add_kernel<<<782, 256, 0, stream>>>(off, psum, cursor);
    scatter_kernel<<<1563, 256, 0, stream>>>(ei, ea, cursor, srcs, eaf);

    ushort_t* xbuf[2] = {xb0, xb1};
    for (int l = 0; l < LL; ++l) {
        ushort_t* xin  = xbuf[l & 1];
        ushort_t* xout = xbuf[(l + 1) & 1];
        agg_kernel<<<NN / 8, 256, 0, stream>>>(off, srcs, eaf, We, be, xin, U);
        if (l == LL - 1) {
            mlp_kernel<1><<<NN / 64, 256, 0, stream>>>(
                U, Wc1 + l * 65536, Wc2 + l * 65536, b1 + l * HDIM, b2 + l * HDIM,
                lng + l * HDIM, lnb + l * HDIM, xin, xout, x);
        } else {
            mlp_kernel<0><<<NN / 64, 256, 0, stream>>>(
                U, Wc1 + l * 65536, Wc2 + l * 65536, b1 + l * HDIM, b2 + l * HDIM,
                lng + l * HDIM, lnb + l * HDIM, xin, xout, nullptr);
        }
    }
}

// Round 4
// 1362.471 us; speedup vs baseline: 2.5859x; 1.0159x over previous
//
#include <hip/hip_runtime.h>
#include <hip/hip_bf16.h>

#define NN 200000
#define EE 400000
#define HDIM 256
#define LL 4
#define FEAT 10

typedef unsigned short ushort_t;
typedef __attribute__((ext_vector_type(8))) short bf16x8;
typedef __attribute__((ext_vector_type(8))) unsigned short u16x8;
typedef __attribute__((ext_vector_type(4))) float f32x4;
typedef __attribute__((ext_vector_type(4))) unsigned int u32x4;

__device__ inline ushort_t f2bf(float f) {
    unsigned int u = __builtin_bit_cast(unsigned int, f);
    return (ushort_t)((u + 0x7fffu + ((u >> 16) & 1u)) >> 16);
}
__device__ inline float bf2f(ushort_t s) {
    unsigned int u = ((unsigned int)s) << 16;
    return __builtin_bit_cast(float, u);
}
__device__ inline float silu_f(float v) { return v / (1.0f + __expf(-v)); }

// x is stored in global PRE-SWIZZLED: row n, true 16B-chunk c lives at chunk (c ^ (n&7)).

// ---------------- node init: xb = LN(silu(emb[z] + feat@Wf + bf)); 32 lanes/node
__global__ __launch_bounds__(256) void node_init_kernel(
    const int* __restrict__ z, const float* __restrict__ feat,
    const float* __restrict__ emb, const float* __restrict__ Wf,
    const float* __restrict__ bfv, const float* __restrict__ g0,
    const float* __restrict__ b0, ushort_t* __restrict__ xb)
{
    int n = blockIdx.x * 8 + (threadIdx.x >> 5);
    int nl = threadIdx.x & 31, c0 = nl * 8;
    int zi = z[n];
    float a[8];
    {
        f32x4 e0 = *(const f32x4*)&emb[(size_t)zi * HDIM + c0];
        f32x4 e1 = *(const f32x4*)&emb[(size_t)zi * HDIM + c0 + 4];
        f32x4 v0 = *(const f32x4*)&bfv[c0];
        f32x4 v1 = *(const f32x4*)&bfv[c0 + 4];
        #pragma unroll
        for (int j = 0; j < 4; ++j) { a[j] = e0[j] + v0[j]; a[4 + j] = e1[j] + v1[j]; }
    }
    #pragma unroll
    for (int f = 0; f < FEAT; ++f) {
        float sf = feat[n * FEAT + f];
        f32x4 w0 = *(const f32x4*)&Wf[f * HDIM + c0];
        f32x4 w1 = *(const f32x4*)&Wf[f * HDIM + c0 + 4];
        #pragma unroll
        for (int j = 0; j < 4; ++j) { a[j] += sf * w0[j]; a[4 + j] += sf * w1[j]; }
    }
    float s = 0.f, q = 0.f;
    #pragma unroll
    for (int c = 0; c < 8; ++c) { a[c] = silu_f(a[c]); s += a[c]; q += a[c] * a[c]; }
    #pragma unroll
    for (int o = 16; o; o >>= 1) { s += __shfl_xor(s, o, 64); q += __shfl_xor(q, o, 64); }
    float mu = s * (1.0f / HDIM);
    float var = q * (1.0f / HDIM) - mu * mu;
    float rs = rsqrtf(var + 1e-5f);
    u16x8 o8;
    #pragma unroll
    for (int c = 0; c < 8; ++c) {
        float g = g0[c0 + c], b = b0[c0 + c];
        o8[c] = f2bf((a[c] - mu) * rs * g + b);
    }
    *(u16x8*)&xb[((size_t)n << 8) + ((nl ^ (n & 7)) << 3)] = o8;
}

__global__ __launch_bounds__(256) void batch_out_kernel(
    const int* __restrict__ batch, float* __restrict__ out)
{
    int i = blockIdx.x * 256 + threadIdx.x;
    if (i < NN) out[i] = (float)batch[i];
}

// ---------------- CSR build
__global__ __launch_bounds__(256) void hist_kernel(const int* __restrict__ ei, int* __restrict__ deg)
{
    int i = blockIdx.x * 256 + threadIdx.x;
    if (i < EE) atomicAdd(&deg[ei[EE + i]], 1);
}

__global__ __launch_bounds__(256) void scan_blocks_kernel(
    const int* __restrict__ deg, int* __restrict__ off, int* __restrict__ psum)
{
    int blk = blockIdx.x, t = threadIdx.x;
    int base = blk * 1024 + t * 4;
    int v[4];
    #pragma unroll
    for (int i = 0; i < 4; ++i) v[i] = (base + i < NN) ? deg[base + i] : 0;
    int s = v[0] + v[1] + v[2] + v[3];
    int lane = t & 63, w = t >> 6;
    int ps = s;
    #pragma unroll
    for (int o = 1; o < 64; o <<= 1) { int u = __shfl_up(ps, o, 64); if (lane >= o) ps += u; }
    __shared__ int wt[4];
    if (lane == 63) wt[w] = ps;
    __syncthreads();
    int wbase = 0;
    for (int k = 0; k < w; ++k) wbase += wt[k];
    int run = wbase + ps - s;
    #pragma unroll
    for (int i = 0; i < 4; ++i) {
        if (base + i < NN) off[base + i] = run;
        run += v[i];
    }
    if (t == 255) psum[blk] = wbase + ps;
}

__global__ __launch_bounds__(256) void scan_top_kernel(int* __restrict__ psum, int nb)
{
    int t = threadIdx.x;
    int v = (t < nb) ? psum[t] : 0;
    int lane = t & 63, w = t >> 6;
    int ps = v;
    #pragma unroll
    for (int o = 1; o < 64; o <<= 1) { int u = __shfl_up(ps, o, 64); if (lane >= o) ps += u; }
    __shared__ int wt[4];
    if (lane == 63) wt[w] = ps;
    __syncthreads();
    int wbase = 0;
    for (int k = 0; k < w; ++k) wbase += wt[k];
    if (t < nb) psum[t] = wbase + ps - v;
}

__global__ __launch_bounds__(256) void scan_add_kernel(
    int* __restrict__ off, const int* __restrict__ psum, int* __restrict__ cursor)
{
    int i = blockIdx.x * 256 + threadIdx.x;
    if (i < NN) {
        int o = off[i] + psum[i >> 10];
        off[i] = o;
        cursor[i] = o;
        if (i == NN - 1) off[NN] = EE;
    }
}

__global__ __launch_bounds__(256) void scatter_kernel(
    const int* __restrict__ ei, const float* __restrict__ ea,
    int* __restrict__ cursor, int* __restrict__ srcs, float4* __restrict__ eaf)
{
    int i = blockIdx.x * 256 + threadIdx.x;
    if (i < EE) {
        int dst = ei[EE + i];
        int pos = atomicAdd(&cursor[dst], 1);
        srcs[pos] = ei[i];
        eaf[pos] = ((const float4*)ea)[i];
    }
}

// ---------------- weights: W[l][k][n] f32 -> per-wave fragment-contiguous bf16
// Wc[l][cbi][s][nf][lane][e] = bf16(W[l][s*32 + (lane>>4)*8 + e][cbi*64 + nf*16 + (lane&15)])
__global__ __launch_bounds__(256) void prep_w_kernel(
    const float* __restrict__ W1, const float* __restrict__ W2,
    ushort_t* __restrict__ Wc1, ushort_t* __restrict__ Wc2)
{
    int idx = blockIdx.x * 256 + threadIdx.x;   // 2 * 4 * 65536
    int which = idx >> 18;
    int rem = idx & 0x3FFFF;
    int l = rem >> 16;
    int t = rem & 0xFFFF;
    int e = t & 7;
    int lane = (t >> 3) & 63;
    int nf = (t >> 9) & 3;
    int s = (t >> 11) & 7;
    int cbi = t >> 14;
    int n = cbi * 64 + nf * 16 + (lane & 15);
    int k = s * 32 + (lane >> 4) * 8 + e;
    const float* W = which ? W2 : W1;
    ushort_t* Wc = which ? Wc2 : Wc1;
    Wc[rem] = f2bf(W[l * 65536 + k * 256 + n]);
}

// ---------------- fused layer: agg -> MLP -> LN
// block = 64 rows; 256 thr (4 waves); wave w owns cols w*64..+63
template<int LAST>
__global__ __launch_bounds__(256, 4) void layer_kernel(
    const int* __restrict__ off, const int* __restrict__ srcs,
    const float4* __restrict__ eaf, const float* __restrict__ We,
    const float* __restrict__ be, const ushort_t* __restrict__ Wc1,
    const ushort_t* __restrict__ Wc2, const float* __restrict__ b1,
    const float* __restrict__ b2, const float* __restrict__ lng,
    const float* __restrict__ lnb, const ushort_t* __restrict__ xin,
    ushort_t* __restrict__ xout, float* __restrict__ xf32)
{
    __shared__ ushort_t sA[64][256];      // U tile -> t tile -> out tile (swizzled)
    __shared__ float sRed[4][64][2];
    const int tid = threadIdx.x;
    const int m0 = blockIdx.x * 64;
    const int lane = tid & 63;
    const int w = tid >> 6;
    const int cb = w * 64;
    const int lg = lane >> 4;
    const int ll = lane & 15;

    // ---- Phase A: aggregate U = x_self + sum relu(x[src] + silu(ea@We+be)) into sA
    {
        const int g = tid >> 5;
        const int nl = tid & 31;
        const int c0 = nl * 8;
        float wv[4][8], bev[8];
        #pragma unroll
        for (int r4 = 0; r4 < 4; ++r4)
            #pragma unroll
            for (int j = 0; j < 8; ++j) wv[r4][j] = We[r4 * HDIM + c0 + j];
        #pragma unroll
        for (int j = 0; j < 8; ++j) bev[j] = be[c0 + j];
        for (int i = 0; i < 8; ++i) {
            int r = g * 8 + i;
            int n = m0 + r;
            u16x8 xs = *(const u16x8*)&xin[((size_t)n << 8) + ((nl ^ (r & 7)) << 3)];
            float acc[8];
            #pragma unroll
            for (int j = 0; j < 8; ++j) acc[j] = bf2f(xs[j]);
            int beg = off[n], end = off[n + 1];
            for (int p = beg; p < end; ++p) {
                int src = srcs[p];
                float4 av = eaf[p];
                u16x8 xg = *(const u16x8*)&xin[((size_t)src << 8) + ((nl ^ (src & 7)) << 3)];
                #pragma unroll
                for (int j = 0; j < 8; ++j) {
                    float e = silu_f(bev[j] + av.x * wv[0][j] + av.y * wv[1][j]
                                            + av.z * wv[2][j] + av.w * wv[3][j]);
                    acc[j] += fmaxf(bf2f(xg[j]) + e, 0.f);
                }
            }
            u16x8 o8;
            #pragma unroll
            for (int j = 0; j < 8; ++j) o8[j] = f2bf(acc[j]);
            *(u16x8*)&sA[r][(nl ^ (r & 7)) << 3] = o8;
        }
    }
    __syncthreads();

    f32x4 acc[4][4] = {};

    // ---- GEMM1: acc = U @ W1 (B fragments straight from global, L2-hot)
    {
        const ushort_t* wp = Wc1 + (w << 14);
        #pragma unroll 2
        for (int s = 0; s < 8; ++s) {
            bf16x8 bfr[4];
            #pragma unroll
            for (int nf = 0; nf < 4; ++nf)
                bfr[nf] = *(const bf16x8*)(wp + ((s * 4 + nf) << 9) + (lane << 3));
            bf16x8 af[4];
            #pragma unroll
            for (int m = 0; m < 4; ++m) {
                int r = m * 16 + ll;
                af[m] = *(const bf16x8*)&sA[r][(((s * 4 + lg) ^ (r & 7)) << 3)];
            }
            #pragma unroll
            for (int m = 0; m < 4; ++m)
                #pragma unroll
                for (int nf = 0; nf < 4; ++nf)
                    acc[m][nf] = __builtin_amdgcn_mfma_f32_16x16x32_bf16(
                        af[m], bfr[nf], acc[m][nf], 0, 0, 0);
        }
    }
    __syncthreads();   // all GEMM1 reads of sA done

    // ---- t = silu(acc + b1) -> sA (swizzled); reset acc
    {
        float bv1[4];
        #pragma unroll
        for (int nf = 0; nf < 4; ++nf) bv1[nf] = b1[cb + nf * 16 + ll];
        #pragma unroll
        for (int m = 0; m < 4; ++m)
            #pragma unroll
            for (int nf = 0; nf < 4; ++nf)
                #pragma unroll
                for (int j = 0; j < 4; ++j) {
                    int r = m * 16 + lg * 4 + j;
                    int c = cb + nf * 16 + ll;
                    sA[r][((((c >> 3) ^ (r & 7)) << 3) | (c & 7))] =
                        f2bf(silu_f(acc[m][nf][j] + bv1[nf]));
                    acc[m][nf][j] = 0.f;
                }
    }
    __syncthreads();

    // ---- GEMM2: acc = t @ W2
    {
        const ushort_t* wp = Wc2 + (w << 14);
        #pragma unroll 2
        for (int s = 0; s < 8; ++s) {
            bf16x8 bfr[4];
            #pragma unroll
            for (int nf = 0; nf < 4; ++nf)
                bfr[nf] = *(const bf16x8*)(wp + ((s * 4 + nf) << 9) + (lane << 3));
            bf16x8 af[4];
            #pragma unroll
            for (int m = 0; m < 4; ++m) {
                int r = m * 16 + ll;
                af[m] = *(const bf16x8*)&sA[r][(((s * 4 + lg) ^ (r & 7)) << 3)];
            }
            #pragma unroll
            for (int m = 0; m < 4; ++m)
                #pragma unroll
                for (int nf = 0; nf < 4; ++nf)
                    acc[m][nf] = __builtin_amdgcn_mfma_f32_16x16x32_bf16(
                        af[m], bfr[nf], acc[m][nf], 0, 0, 0);
        }
    }

    // ---- residual (scattered xin re-read, L1/L2-hot) + per-row LN stats
    float bv2[4], gvv[4], bbv[4];
    #pragma unroll
    for (int nf = 0; nf < 4; ++nf) {
        int c = cb + nf * 16 + ll;
        bv2[nf] = b2[c]; gvv[nf] = lng[c]; bbv[nf] = lnb[c];
    }
    #pragma unroll
    for (int m = 0; m < 4; ++m) {
        #pragma unroll
        for (int j = 0; j < 4; ++j) {
            int r = m * 16 + lg * 4 + j;
            size_t rowb = ((size_t)(m0 + r)) << 8;
            float s = 0.f, q = 0.f;
            #pragma unroll
            for (int nf = 0; nf < 4; ++nf) {
                int c = cb + nf * 16 + ll;
                float xres = bf2f(xin[rowb + ((((c >> 3) ^ (r & 7)) << 3) | (c & 7))]);
                float val = acc[m][nf][j] + bv2[nf] + xres;
                acc[m][nf][j] = val;
                s += val; q += val * val;
            }
            #pragma unroll
            for (int o = 1; o < 16; o <<= 1) {
                s += __shfl_xor(s, o, 64);
                q += __shfl_xor(q, o, 64);
            }
            if (ll == 0) { sRed[w][r][0] = s; sRed[w][r][1] = q; }
        }
    }
    __syncthreads();   // sRed ready; also guards sA(t) overwrite below

    // ---- finalize LN; write out
    #pragma unroll
    for (int m = 0; m < 4; ++m) {
        #pragma unroll
        for (int j = 0; j < 4; ++j) {
            int r = m * 16 + lg * 4 + j;
            float s = sRed[0][r][0] + sRed[1][r][0] + sRed[2][r][0] + sRed[3][r][0];
            float q = sRed[0][r][1] + sRed[1][r][1] + sRed[2][r][1] + sRed[3][r][1];
            float mu = s * (1.0f / HDIM);
            float var = q * (1.0f / HDIM) - mu * mu;
            float rs = rsqrtf(var + 1e-5f);
            if (LAST) {
                size_t rowb = ((size_t)(m0 + r)) << 8;
                #pragma unroll
                for (int nf = 0; nf < 4; ++nf) {
                    int c = cb + nf * 16 + ll;
                    xf32[rowb + c] = (acc[m][nf][j] - mu) * rs * gvv[nf] + bbv[nf];
                }
            } else {
                #pragma unroll
                for (int nf = 0; nf < 4; ++nf) {
                    int c = cb + nf * 16 + ll;
                    sA[r][((((c >> 3) ^ (r & 7)) << 3) | (c & 7))] =
                        f2bf((acc[m][nf][j] - mu) * rs * gvv[nf] + bbv[nf]);
                }
            }
        }
    }
    if (!LAST) {
        __syncthreads();
        // linear copy-out (xout stays swizzled in global)
        #pragma unroll
        for (int it = 0; it < 8; ++it) {
            int idx = tid + it * 256;
            u32x4 v = *(const u32x4*)((const ushort_t*)sA + (idx << 3));
            *(u32x4*)(xout + (((size_t)m0) << 8) + (idx << 3)) = v;
        }
    }
}

extern "C" void kernel_launch(void* const* d_in, const int* in_sizes, int n_in,
                              void* d_out, int out_size, void* d_ws, size_t ws_size,
                              hipStream_t stream)
{
    const int*   z    = (const int*)d_in[0];
    const float* feat = (const float*)d_in[1];
    const int*   ei   = (const int*)d_in[2];
    const float* ea   = (const float*)d_in[3];
    const int*   batch= (const int*)d_in[4];
    const float* emb  = (const float*)d_in[5];
    const float* Wf   = (const float*)d_in[6];
    const float* bfv  = (const float*)d_in[7];
    const float* g0   = (const float*)d_in[8];
    const float* b0   = (const float*)d_in[9];
    const float* We   = (const float*)d_in[10];
    const float* be   = (const float*)d_in[11];
    const float* W1   = (const float*)d_in[12];
    const float* b1   = (const float*)d_in[13];
    const float* W2   = (const float*)d_in[14];
    const float* b2   = (const float*)d_in[15];
    const float* lng  = (const float*)d_in[16];
    const float* lnb  = (const float*)d_in[17];

    float* x    = (float*)d_out;
    float* outb = (float*)d_out + (size_t)NN * HDIM;

    char* ws = (char*)d_ws;
    ushort_t* xb0  = (ushort_t*)ws;                         // 102,400,000 B
    ushort_t* xb1  = (ushort_t*)(ws + 102400000);           // 102,400,000 B
    float4*   eaf  = (float4*)(ws + 204800000);             // 6,400,000 B
    int*      srcs = (int*)(ws + 211200000);                // 1,600,000 B
    int*      off  = (int*)(ws + 212800000);                // 800,016 B
    int*      cursor = (int*)(ws + 213600016);              // 800,000 B
    int*      deg  = (int*)(ws + 214400016);                // 800,000 B
    int*      psum = (int*)(ws + 215200016);                // 1,008 B
    ushort_t* Wc1  = (ushort_t*)(ws + 215201024);           // 524,288 B
    ushort_t* Wc2  = Wc1 + LL * HDIM * HDIM;                // 524,288 B

    prep_w_kernel<<<2048, 256, 0, stream>>>(W1, W2, Wc1, Wc2);
    batch_out_kernel<<<782, 256, 0, stream>>>(batch, outb);
    node_init_kernel<<<NN / 8, 256, 0, stream>>>(z, feat, emb, Wf, bfv, g0, b0, xb0);

    hipMemsetAsync(deg, 0, NN * sizeof(int), stream);
    hist_kernel<<<1563, 256, 0, stream>>>(ei, deg);
    scan_blocks_kernel<<<196, 256, 0, stream>>>(deg, off, psum);
    scan_top_kernel<<<1, 256, 0, stream>>>(psum, 196);
    scan_add_kernel<<<782, 256, 0, stream>>>(off, psum, cursor);
    scatter_kernel<<<1563, 256, 0, stream>>>(ei, ea, cursor, srcs, eaf);

    ushort_t* xbuf[2] = {xb0, xb1};
    for (int l = 0; l < LL; ++l) {
        ushort_t* xin  = xbuf[l & 1];
        ushort_t* xout = xbuf[(l + 1) & 1];
        if (l == LL - 1) {
            layer_kernel<1><<<NN / 64, 256, 0, stream>>>(
                off, srcs, eaf, We, be, Wc1 + l * 65536, Wc2 + l * 65536,
                b1 + l * HDIM, b2 + l * HDIM, lng + l * HDIM, lnb + l * HDIM,
                xin, xout, x);
        } else {
            layer_kernel<0><<<NN / 64, 256, 0, stream>>>(
                off, srcs, eaf, We, be, Wc1 + l * 65536, Wc2 + l * 65536,
                b1 + l * HDIM, b2 + l * HDIM, lng + l * HDIM, lnb + l * HDIM,
                xin, xout, nullptr);
        }
    }
}